// Round 6
// baseline (183.371 us; speedup 1.0000x reference)
//
#include <hip/hip_runtime.h>
#include <hip/hip_cooperative_groups.h>
#include <math.h>

namespace cg = cooperative_groups;

// Problem constants (from reference setup_inputs)
constexpr int B = 8, N = 2048, H = 512, M = 96, S = 16;
constexpr int E = 256, D = 64, R = 5, MAXD = 600;
constexpr int NZ = 64;            // n-splits for sent max partial
constexpr int NCHUNK = N / NZ;    // 32
constexpr int MT2 = 4;            // mentions per gemm block (full-H, coop)
constexpr int MT  = 8;            // mentions per gemm block (fallback)
constexpr int HC = 4;             // h-chunks (fallback gemm)
constexpr int HCHUNK = H / HC;    // 128
constexpr int MT4 = 8;            // m-rows per final-max tile
constexpr float NEG_INF = -1e10f;

constexpr int P1_SENT  = 256;                     // sent-partial items (2 z each)
constexpr int P1_ITEMS = P1_SENT + 2 * B * M;     // 1792
constexpr int NGEMM    = (M / MT2) * B * 2;       // 384
constexpr int P2_ITEMS = NGEMM + B + MAXD / 4;    // 542
constexpr int P3_ITEMS = (M / MT4) * B;           // 96

__device__ inline void atomicMaxFloat(float* addr, float val) {
    int* ai = (int*)addr;
    int old = *ai;
    while (__int_as_float(old) < val) {
        int assumed = old;
        old = atomicCAS(ai, assumed, __float_as_int(val));
        if (old == assumed) break;
    }
}

// ===========================================================================
// Cooperative single-kernel path. All phases grid-stride over gridDim.x.
// ===========================================================================
__global__ __launch_bounds__(256, 4)
void k_all(const float* __restrict__ node,
           const int* __restrict__ cmap, const float* __restrict__ cmask,
           const int* __restrict__ dmap, const float* __restrict__ dmask,
           const int* __restrict__ distance,
           const float* __restrict__ Wc, const float* __restrict__ bc,
           const float* __restrict__ Wd, const float* __restrict__ bd,
           const float* __restrict__ Wsc, const float* __restrict__ bsc,
           const float* __restrict__ emb,
           float* __restrict__ part, float* __restrict__ pooled,
           float* __restrict__ validAB, float* __restrict__ sS,
           float* __restrict__ sAB, float* __restrict__ sD,
           float* __restrict__ out) {
    cg::grid_group grid = cg::this_grid();
    const int t = threadIdx.x;
    const int blk = blockIdx.x;
    const int GD = gridDim.x;

    __shared__ float4 lp4[MT2][H / 4];     // 8 KB   (phase-2 gemm)
    __shared__ int    smap[S];
    __shared__ float  smask[S];
    __shared__ float  sent[H];             // 2 KB   (phase-2 sent score)
    __shared__ float  red2[4][MT2 * R];    // 320 B
    __shared__ float  red[R][4];
    __shared__ float  lB[M * R];           // 1.9 KB (phase 3)
    __shared__ float  lD[MAXD * R];        // 12 KB
    __shared__ float  lA[MT4 * R];
    __shared__ float  lvA[MT4], lvB[M];

    // ---------------- Phase 1: sent partial max + span pooling ----------------
    for (int item = blk; item < P1_ITEMS; item += GD) {
        if (item < P1_SENT) {
            int b = item >> 5;
            int z = ((item & 31) << 1) + (t >> 7);
            int tt = t & 127;   // float4 index over H
            const float4* p = reinterpret_cast<const float4*>(
                node + ((size_t)b * N + (size_t)z * NCHUNK) * H) + tt;
            float4 mx = p[0];
            #pragma unroll
            for (int n = 1; n < NCHUNK; ++n) {
                float4 v = p[(size_t)n * (H / 4)];
                mx.x = fmaxf(mx.x, v.x); mx.y = fmaxf(mx.y, v.y);
                mx.z = fmaxf(mx.z, v.z); mx.w = fmaxf(mx.w, v.w);
            }
            reinterpret_cast<float4*>(part + ((size_t)z * B + b) * H)[tt] = mx;
        } else {
            int j = item - P1_SENT;
            int m = j % M, b = (j / M) % B, z = j / (M * B);
            const int*   map  = z ? dmap  : cmap;
            const float* mask = z ? dmask : cmask;
            __syncthreads();               // protect smap/smask across loop iters
            if (t < S) {
                size_t off = ((size_t)b * M + m) * S + t;
                smap[t]  = map[off];
                smask[t] = mask[off];
            }
            __syncthreads();
            float a0 = 0.f, a1 = 0.f;
            #pragma unroll
            for (int s = 0; s < S; ++s) {
                float mk = smask[s];
                const float2 v = reinterpret_cast<const float2*>(
                    node + ((size_t)b * N + smap[s]) * H)[t];
                a0 += mk * v.x; a1 += mk * v.y;
            }
            size_t row = ((size_t)z * B + b) * M + m;
            reinterpret_cast<float2*>(pooled + row * H)[t] = make_float2(a0, a1);
            if (t == 0) {
                float ms = 0.f;
                #pragma unroll
                for (int s = 0; s < S; ++s) ms += smask[s];
                validAB[row] = (ms > 0.f) ? 1.f : 0.f;
            }
        }
    }
    if (blk == 0 && t < B * R) out[t] = NEG_INF;   // init for phase-3 atomicMax

    grid.sync();

    // ---------------- Phase 2: entity GEMM+proj | sent score | dist table -----
    for (int item = blk; item < P2_ITEMS; item += GD) {
        __syncthreads();                   // protect shared reuse across iters
        if (item < NGEMM) {
            int mg = item % (M / MT2);
            int b  = (item / (M / MT2)) % B;
            int z  = item / ((M / MT2) * B);
            const float* W    = z ? Wd : Wc;
            const float* bias = z ? bd : bc;
            int scoff = z ? E : 0;

            for (int i = t; i < MT2 * (H / 4); i += 256) {   // 512 float4
                int mi = i >> 7, c4 = i & 127;
                lp4[mi][c4] = reinterpret_cast<const float4*>(
                    pooled + (((size_t)z * B + b) * M + mg * MT2 + mi) * H)[c4];
            }
            __syncthreads();

            float acc[MT2] = {};
            const float* Wp = W + t;
            for (int h = 0; h < H; h += 4) {
                float w0 = Wp[(size_t)(h + 0) * E];
                float w1 = Wp[(size_t)(h + 1) * E];
                float w2 = Wp[(size_t)(h + 2) * E];
                float w3 = Wp[(size_t)(h + 3) * E];
                #pragma unroll
                for (int mi = 0; mi < MT2; ++mi) {
                    const float4 pv = lp4[mi][h >> 2];
                    acc[mi] += pv.x * w0 + pv.y * w1 + pv.z * w2 + pv.w * w3;
                }
            }
            float be = bias[t];
            float v[MT2];
            #pragma unroll
            for (int mi = 0; mi < MT2; ++mi) v[mi] = tanhf(acc[mi] + be);

            float w5[R];
            #pragma unroll
            for (int r = 0; r < R; ++r) w5[r] = Wsc[(size_t)(scoff + t) * R + r];
            int wave = t >> 6, lane = t & 63;
            #pragma unroll
            for (int mi = 0; mi < MT2; ++mi) {
                #pragma unroll
                for (int r = 0; r < R; ++r) {
                    float p = v[mi] * w5[r];
                    for (int off = 32; off; off >>= 1) p += __shfl_down(p, off, 64);
                    if (lane == 0) red2[wave][mi * R + r] = p;
                }
            }
            __syncthreads();
            if (t < MT2 * R) {
                float s = red2[0][t] + red2[1][t] + red2[2][t] + red2[3][t];
                int mi = t / R, r = t % R;
                sAB[(((size_t)z * B + b) * M + mg * MT2 + mi) * R + r] = s;
            }
        } else if (item < NGEMM + B) {
            int b = item - NGEMM;
            for (int h = t; h < H; h += 256) {
                float mx = -INFINITY;
                for (int z = 0; z < NZ; ++z) mx = fmaxf(mx, part[((size_t)z * B + b) * H + h]);
                sent[h] = mx;
            }
            __syncthreads();
            float acc[R] = {};
            for (int h = t; h < H; h += 256) {
                float v = sent[h];
                const float* w = Wsc + (size_t)(2 * E + D + h) * R;
                #pragma unroll
                for (int r = 0; r < R; ++r) acc[r] += v * w[r];
            }
            int wave = t >> 6, lane = t & 63;
            #pragma unroll
            for (int r = 0; r < R; ++r) {
                float v = acc[r];
                for (int off = 32; off; off >>= 1) v += __shfl_down(v, off, 64);
                if (lane == 0) red[r][wave] = v;
            }
            __syncthreads();
            if (t < R) sS[b * R + t] = red[t][0] + red[t][1] + red[t][2] + red[t][3] + bsc[t];
        } else {
            int d = (item - NGEMM - B) * 4 + (t >> 6);
            int k = t & 63;
            float v = emb[(size_t)d * D + k];
            #pragma unroll
            for (int r = 0; r < R; ++r) {
                float p = v * Wsc[(size_t)(2 * E + k) * R + r];
                for (int off = 32; off; off >>= 1) p += __shfl_down(p, off, 64);
                if (k == 0) sD[d * R + r] = p;
            }
        }
    }

    grid.sync();

    // ---------------- Phase 3: pairwise max ----------------
    for (int item = blk; item < P3_ITEMS; item += GD) {
        int g = item % (M / MT4);
        int b = item / (M / MT4);
        __syncthreads();                   // protect shared reuse across iters

        for (int i = t; i < M * R; i += 256) lB[i] = sAB[((size_t)(B + b)) * M * R + i];
        for (int i = t; i < MAXD * R; i += 256) lD[i] = sD[i];
        if (t < MT4 * R) lA[t] = sAB[((size_t)b * M + g * MT4) * R + t] + sS[b * R + (t % R)];
        if (t < MT4) lvA[t] = validAB[(size_t)b * M + g * MT4 + t];
        for (int i = t; i < M; i += 256) lvB[i] = validAB[((size_t)B + b) * M + i];
        __syncthreads();

        float mx[R];
        #pragma unroll
        for (int r = 0; r < R; ++r) mx[r] = NEG_INF;

        #pragma unroll
        for (int it = 0; it < (MT4 * M) / 256; ++it) {
            int idx = it * 256 + t;           // [0, 768)
            int mi = idx / M, n = idx % M;
            int dist = distance[((size_t)b * M + g * MT4 + mi) * M + n];
            if (lvA[mi] > 0.f && lvB[n] > 0.f && dist >= 0 /*DIST_THRESH*/) {
                #pragma unroll
                for (int r = 0; r < R; ++r)
                    mx[r] = fmaxf(mx[r], lA[mi * R + r] + lB[n * R + r] + lD[dist * R + r]);
            }
        }
        int wave = t >> 6, lane = t & 63;
        #pragma unroll
        for (int r = 0; r < R; ++r) {
            float v = mx[r];
            for (int off = 32; off; off >>= 1) v = fmaxf(v, __shfl_down(v, off, 64));
            if (lane == 0) red[r][wave] = v;
        }
        __syncthreads();
        if (t < R) {
            float v = fmaxf(fmaxf(red[t][0], red[t][1]), fmaxf(red[t][2], red[t][3]));
            atomicMaxFloat(out + b * R + t, v);
        }
    }
}

// ===========================================================================
// Fallback path: the validated 4-kernel pipeline from round 4 (61 us).
// ===========================================================================
constexpr int K1_SENT = 256;
constexpr int K1_POOL = 2 * B * M;              // 1536
constexpr int K2_GEMM = (M / MT) * B * 2 * HC;  // 768
constexpr int K2_SENT = B;
constexpr int K2_DIST = MAXD / 4;

__global__ void k1(const float* __restrict__ node,
                   const int* __restrict__ cmap, const float* __restrict__ cmask,
                   const int* __restrict__ dmap, const float* __restrict__ dmask,
                   float* __restrict__ part, float* __restrict__ pooled,
                   float* __restrict__ validAB) {
    int blk = blockIdx.x, t = threadIdx.x;
    __shared__ int   smap[S];
    __shared__ float smask[S];
    if (blk < K1_SENT) {
        int b = blk >> 5;
        int z = ((blk & 31) << 1) + (t >> 7);
        int tt = t & 127;
        const float4* p = reinterpret_cast<const float4*>(
            node + ((size_t)b * N + (size_t)z * NCHUNK) * H) + tt;
        float4 mx = p[0];
        #pragma unroll
        for (int n = 1; n < NCHUNK; ++n) {
            float4 v = p[(size_t)n * (H / 4)];
            mx.x = fmaxf(mx.x, v.x); mx.y = fmaxf(mx.y, v.y);
            mx.z = fmaxf(mx.z, v.z); mx.w = fmaxf(mx.w, v.w);
        }
        reinterpret_cast<float4*>(part + ((size_t)z * B + b) * H)[tt] = mx;
    } else {
        int j = blk - K1_SENT;
        int m = j % M, b = (j / M) % B, z = j / (M * B);
        const int*   map  = z ? dmap  : cmap;
        const float* mask = z ? dmask : cmask;
        if (t < S) {
            size_t off = ((size_t)b * M + m) * S + t;
            smap[t]  = map[off];
            smask[t] = mask[off];
        }
        __syncthreads();
        float a0 = 0.f, a1 = 0.f;
        #pragma unroll
        for (int s = 0; s < S; ++s) {
            float mk = smask[s];
            const float2 v = reinterpret_cast<const float2*>(
                node + ((size_t)b * N + smap[s]) * H)[t];
            a0 += mk * v.x; a1 += mk * v.y;
        }
        size_t row = ((size_t)z * B + b) * M + m;
        reinterpret_cast<float2*>(pooled + row * H)[t] = make_float2(a0, a1);
        if (t == 0) {
            float ms = 0.f;
            #pragma unroll
            for (int s = 0; s < S; ++s) ms += smask[s];
            validAB[row] = (ms > 0.f) ? 1.f : 0.f;
        }
    }
}

__global__ void k2(const float* __restrict__ pooled,
                   const float* __restrict__ Wc, const float* __restrict__ Wd,
                   const float* __restrict__ part, const float* __restrict__ Wsc,
                   const float* __restrict__ bsc, const float* __restrict__ emb,
                   float* __restrict__ dotp, float* __restrict__ sS,
                   float* __restrict__ sD, float* __restrict__ out) {
    int blk = blockIdx.x, t = threadIdx.x;
    __shared__ float lp[MT][HCHUNK];
    __shared__ float sent[H];
    __shared__ float red[R][4];
    if (blk < K2_GEMM) {
        int mg  = blk % (M / MT);
        int b   = (blk / (M / MT)) % B;
        int zhc = blk / ((M / MT) * B);
        int z = zhc >> 2, hc = zhc & 3;
        const float* W = z ? Wd : Wc;
        for (int i = t; i < MT * HCHUNK; i += 256) {
            int mi = i >> 7, hh = i & (HCHUNK - 1);
            lp[mi][hh] = pooled[(((size_t)z * B + b) * M + mg * MT + mi) * H + hc * HCHUNK + hh];
        }
        __syncthreads();
        float acc[MT] = {};
        const float* Wp = W + (size_t)(hc * HCHUNK) * E + t;
        for (int hh = 0; hh < HCHUNK; hh += 4) {
            float w0 = Wp[(size_t)(hh + 0) * E];
            float w1 = Wp[(size_t)(hh + 1) * E];
            float w2 = Wp[(size_t)(hh + 2) * E];
            float w3 = Wp[(size_t)(hh + 3) * E];
            #pragma unroll
            for (int mi = 0; mi < MT; ++mi) {
                const float4 pv = *reinterpret_cast<const float4*>(&lp[mi][hh]);
                acc[mi] += pv.x * w0 + pv.y * w1 + pv.z * w2 + pv.w * w3;
            }
        }
        #pragma unroll
        for (int mi = 0; mi < MT; ++mi) {
            size_t row = ((size_t)z * B + b) * M + mg * MT + mi;
            dotp[((size_t)hc * (2 * B * M) + row) * E + t] = acc[mi];
        }
    } else if (blk < K2_GEMM + K2_SENT) {
        int b = blk - K2_GEMM;
        if (b == 0 && t < B * R) out[t] = NEG_INF;
        for (int h = t; h < H; h += 256) {
            float mx = -INFINITY;
            for (int z = 0; z < NZ; ++z) mx = fmaxf(mx, part[((size_t)z * B + b) * H + h]);
            sent[h] = mx;
        }
        __syncthreads();
        float acc[R] = {};
        for (int h = t; h < H; h += 256) {
            float v = sent[h];
            const float* w = Wsc + (size_t)(2 * E + D + h) * R;
            #pragma unroll
            for (int r = 0; r < R; ++r) acc[r] += v * w[r];
        }
        int wave = t >> 6, lane = t & 63;
        #pragma unroll
        for (int r = 0; r < R; ++r) {
            float v = acc[r];
            for (int off = 32; off; off >>= 1) v += __shfl_down(v, off, 64);
            if (lane == 0) red[r][wave] = v;
        }
        __syncthreads();
        if (t < R) sS[b * R + t] = red[t][0] + red[t][1] + red[t][2] + red[t][3] + bsc[t];
    } else {
        int d = (blk - K2_GEMM - K2_SENT) * 4 + (t >> 6);
        int k = t & 63;
        float v = emb[(size_t)d * D + k];
        #pragma unroll
        for (int r = 0; r < R; ++r) {
            float p = v * Wsc[(size_t)(2 * E + k) * R + r];
            for (int off = 32; off; off >>= 1) p += __shfl_down(p, off, 64);
            if (k == 0) sD[d * R + r] = p;
        }
    }
}

__global__ void k3(const float* __restrict__ dotp,
                   const float* __restrict__ bc, const float* __restrict__ bd,
                   const float* __restrict__ Wsc, const float* __restrict__ sS,
                   float* __restrict__ sAB) {
    int rid = blockIdx.x * 4 + (threadIdx.x >> 6);
    int lane = threadIdx.x & 63;
    int z = rid / (B * M);
    int b = (rid % (B * M)) / M;
    const float* bias = z ? bd : bc;
    int scoff = z ? E : 0;
    float4 dv = make_float4(0.f, 0.f, 0.f, 0.f);
    #pragma unroll
    for (int hc = 0; hc < HC; ++hc) {
        float4 v = reinterpret_cast<const float4*>(dotp + ((size_t)hc * (2 * B * M) + rid) * E)[lane];
        dv.x += v.x; dv.y += v.y; dv.z += v.z; dv.w += v.w;
    }
    float4 bv = reinterpret_cast<const float4*>(bias)[lane];
    float v0 = tanhf(dv.x + bv.x);
    float v1 = tanhf(dv.y + bv.y);
    float v2 = tanhf(dv.z + bv.z);
    float v3 = tanhf(dv.w + bv.w);
    int e0 = scoff + lane * 4;
    float p[R];
    #pragma unroll
    for (int r = 0; r < R; ++r) {
        p[r] = v0 * Wsc[(size_t)(e0 + 0) * R + r] + v1 * Wsc[(size_t)(e0 + 1) * R + r]
             + v2 * Wsc[(size_t)(e0 + 2) * R + r] + v3 * Wsc[(size_t)(e0 + 3) * R + r];
    }
    #pragma unroll
    for (int r = 0; r < R; ++r) {
        for (int off = 32; off; off >>= 1) p[r] += __shfl_down(p[r], off, 64);
    }
    if (lane == 0) {
        #pragma unroll
        for (int r = 0; r < R; ++r) {
            float add = (z == 0) ? sS[b * R + r] : 0.f;
            sAB[(size_t)rid * R + r] = p[r] + add;
        }
    }
}

__global__ void k4(const int* __restrict__ distance,
                   const float* __restrict__ sAB, const float* __restrict__ validAB,
                   const float* __restrict__ sD, float* __restrict__ out) {
    int g = blockIdx.x, b = blockIdx.y;
    int t = threadIdx.x;
    __shared__ float lB[M * R];
    __shared__ float lD[MAXD * R];
    __shared__ float lA[MT4 * R];
    __shared__ float lvA[MT4], lvB[M];
    __shared__ float red[R][4];
    for (int i = t; i < M * R; i += 256) lB[i] = sAB[((size_t)(B + b)) * M * R + i];
    for (int i = t; i < MAXD * R; i += 256) lD[i] = sD[i];
    if (t < MT4 * R) lA[t] = sAB[((size_t)b * M + g * MT4) * R + t];
    if (t < MT4) lvA[t] = validAB[(size_t)b * M + g * MT4 + t];
    for (int i = t; i < M; i += 256) lvB[i] = validAB[((size_t)B + b) * M + i];
    __syncthreads();
    float mx[R];
    #pragma unroll
    for (int r = 0; r < R; ++r) mx[r] = NEG_INF;
    #pragma unroll
    for (int it = 0; it < (MT4 * M) / 256; ++it) {
        int idx = it * 256 + t;
        int mi = idx / M, n = idx % M;
        int dist = distance[((size_t)b * M + g * MT4 + mi) * M + n];
        if (lvA[mi] > 0.f && lvB[n] > 0.f && dist >= 0) {
            #pragma unroll
            for (int r = 0; r < R; ++r)
                mx[r] = fmaxf(mx[r], lA[mi * R + r] + lB[n * R + r] + lD[dist * R + r]);
        }
    }
    int wave = t >> 6, lane = t & 63;
    #pragma unroll
    for (int r = 0; r < R; ++r) {
        float v = mx[r];
        for (int off = 32; off; off >>= 1) v = fmaxf(v, __shfl_down(v, off, 64));
        if (lane == 0) red[r][wave] = v;
    }
    __syncthreads();
    if (t < R) {
        float v = fmaxf(fmaxf(red[t][0], red[t][1]), fmaxf(red[t][2], red[t][3]));
        atomicMaxFloat(out + b * R + t, v);
    }
}

// ---------------------------------------------------------------------------
extern "C" void kernel_launch(void* const* d_in, const int* in_sizes, int n_in,
                              void* d_out, int out_size, void* d_ws, size_t ws_size,
                              hipStream_t stream) {
    const float* node     = (const float*)d_in[0];
    const int*   cmap     = (const int*)  d_in[1];
    const float* cmask    = (const float*)d_in[2];
    const int*   dmap     = (const int*)  d_in[3];
    const float* dmask    = (const float*)d_in[4];
    const int*   distance = (const int*)  d_in[5];
    const float* Wc       = (const float*)d_in[6];
    const float* bc       = (const float*)d_in[7];
    const float* Wd       = (const float*)d_in[8];
    const float* bd       = (const float*)d_in[9];
    const float* Wsc      = (const float*)d_in[10];
    const float* bsc      = (const float*)d_in[11];
    const float* emb      = (const float*)d_in[12];
    float* out = (float*)d_out;

    // workspace layout (floats): total ~10.5 MB
    float* ws      = (float*)d_ws;
    float* part    = ws;                             // NZ*B*H      = 262144
    float* sS      = part + (size_t)NZ * B * H;      // B*R         = 40
    float* sAB     = sS + B * R;                     // 2*B*M*R     = 7680
    float* validAB = sAB + 2 * B * M * R;            // 2*B*M       = 1536
    float* sD      = validAB + 2 * B * M;            // MAXD*R      = 3000
    float* pooled  = sD + MAXD * R;                  // 2*B*M*H     = 786432
    float* dotp    = pooled + (size_t)2 * B * M * H; // HC*2*B*M*E  = 1572864 (fallback only)

    // Size the cooperative grid from the runtime's own occupancy calc.
    int occ = 0;
    hipError_t qerr = hipOccupancyMaxActiveBlocksPerMultiprocessor(&occ, k_all, 256, 0);
    int grid = occ * 256;                 // 256 CUs on MI355X
    if (grid > 1024) grid = 1024;

    hipError_t lerr = hipErrorUnknown;
    if (qerr == hipSuccess && grid >= 64) {
        void* args[] = {
            (void*)&node, (void*)&cmap, (void*)&cmask, (void*)&dmap, (void*)&dmask,
            (void*)&distance, (void*)&Wc, (void*)&bc, (void*)&Wd, (void*)&bd,
            (void*)&Wsc, (void*)&bsc, (void*)&emb,
            (void*)&part, (void*)&pooled, (void*)&validAB, (void*)&sS,
            (void*)&sAB, (void*)&sD, (void*)&out
        };
        lerr = hipLaunchCooperativeKernel((void*)k_all, dim3(grid), dim3(256), args, 0, stream);
    }
    if (lerr != hipSuccess) {
        // Fallback: validated 4-kernel pipeline (round 4).
        hipLaunchKernelGGL(k1, dim3(K1_SENT + K1_POOL), dim3(256), 0, stream,
                           node, cmap, cmask, dmap, dmask, part, pooled, validAB);
        hipLaunchKernelGGL(k2, dim3(K2_GEMM + K2_SENT + K2_DIST), dim3(256), 0, stream,
                           pooled, Wc, Wd, part, Wsc, bsc, emb, dotp, sS, sD, out);
        hipLaunchKernelGGL(k3, dim3(2 * B * M / 4), dim3(256), 0, stream,
                           dotp, bc, bd, Wsc, sS, sAB);
        hipLaunchKernelGGL(k4, dim3(M / MT4, B), dim3(256), 0, stream,
                           distance, sAB, validAB, sD, out);
    }
}

// Round 7
// 79.801 us; speedup vs baseline: 2.2979x; 2.2979x over previous
//
#include <hip/hip_runtime.h>
#include <math.h>

// Problem constants (from reference setup_inputs)
constexpr int B = 8, N = 2048, H = 512, M = 96, S = 16;
constexpr int E = 256, D = 64, R = 5, MAXD = 600;
constexpr int NZ = 64;            // n-splits for sent max partial
constexpr int NCHUNK = N / NZ;    // 32
constexpr int MTA = 4;            // mentions per fused gemm block (1 per wave)
constexpr int MT4 = 8;            // m-rows per final-max tile
constexpr float NEG_INF = -1e10f;

constexpr int A_SENT = 256;                 // sent-partial blocks (2 z each)
constexpr int A_GEMM = 2 * B * (M / MTA);   // 384 fused entity blocks
constexpr int A_DIST = MAXD / 4;            // 150
constexpr int A_GRID = A_SENT + A_GEMM + A_DIST;   // 790

__device__ inline void atomicMaxFloat(float* addr, float val) {
    int* ai = (int*)addr;
    int old = *ai;
    while (__int_as_float(old) < val) {
        int assumed = old;
        old = atomicCAS(ai, assumed, __float_as_int(val));
        if (old == assumed) break;
    }
}

// ===========================================================================
// Kernel A: sent-partial max | fused pool+GEMM+tanh+proj | dist table | out init
// ===========================================================================
__global__ void kA(const float* __restrict__ node,
                   const int* __restrict__ cmap, const float* __restrict__ cmask,
                   const int* __restrict__ dmap, const float* __restrict__ dmask,
                   const float* __restrict__ Wc, const float* __restrict__ bc,
                   const float* __restrict__ Wd, const float* __restrict__ bd,
                   const float* __restrict__ Wsc, const float* __restrict__ emb,
                   float* __restrict__ part, float* __restrict__ sAB,
                   float* __restrict__ validAB, float* __restrict__ sD,
                   float* __restrict__ out) {
    const int blk = blockIdx.x;
    const int t = threadIdx.x;

    if (blk == 0 && t < B * R) out[t] = NEG_INF;   // init for kB's atomicMax

    if (blk < A_SENT) {
        // ---- sent partial max: block covers (b, 2 z-chunks) ----
        int b = blk >> 5;
        int z = ((blk & 31) << 1) + (t >> 7);
        int tt = t & 127;   // float4 index over H
        const float4* p = reinterpret_cast<const float4*>(
            node + ((size_t)b * N + (size_t)z * NCHUNK) * H) + tt;
        float4 mx = p[0];
        #pragma unroll
        for (int n = 1; n < NCHUNK; ++n) {
            float4 v = p[(size_t)n * (H / 4)];
            mx.x = fmaxf(mx.x, v.x); mx.y = fmaxf(mx.y, v.y);
            mx.z = fmaxf(mx.z, v.z); mx.w = fmaxf(mx.w, v.w);
        }
        reinterpret_cast<float4*>(part + ((size_t)z * B + b) * H)[tt] = mx;
    } else if (blk < A_SENT + A_GEMM) {
        // ---- fused: gather/pool 4 mentions -> GEMM -> tanh -> rank-5 proj ----
        int j  = blk - A_SENT;
        int mg = j % (M / MTA);
        int b  = (j / (M / MTA)) % B;
        int z  = j / ((M / MTA) * B);
        const float* W    = z ? Wd : Wc;
        const float* bias = z ? bd : bc;
        const int*   map  = z ? dmap  : cmap;
        const float* mask = z ? dmask : cmask;
        int scoff = z ? E : 0;

        __shared__ float pooled[MTA][H];    // 8 KB
        __shared__ int   smap[MTA][S];
        __shared__ float smask[MTA][S];

        if (t < MTA * S) {
            int mi = t >> 4, s = t & 15;
            size_t off = ((size_t)b * M + mg * MTA + mi) * S + s;
            smap[mi][s]  = map[off];
            smask[mi][s] = mask[off];
        }
        __syncthreads();

        // pool: thread t = float2 index over H (256 * 2 = 512)
        #pragma unroll
        for (int mi = 0; mi < MTA; ++mi) {
            float a0 = 0.f, a1 = 0.f;
            #pragma unroll
            for (int s = 0; s < S; ++s) {
                float mk = smask[mi][s];
                const float2 v = reinterpret_cast<const float2*>(
                    node + ((size_t)b * N + smap[mi][s]) * H)[t];
                a0 += mk * v.x; a1 += mk * v.y;
            }
            reinterpret_cast<float2*>(&pooled[mi][0])[t] = make_float2(a0, a1);
        }
        if (t < MTA) {
            float ms = 0.f;
            #pragma unroll
            for (int s = 0; s < S; ++s) ms += smask[t][s];
            validAB[((size_t)z * B + b) * M + mg * MTA + t] = (ms > 0.f) ? 1.f : 0.f;
        }
        __syncthreads();

        // GEMM: wave = mention, lane = e-quad. float4 W loads, unroll 8.
        int eq = t & 63;      // e-quad index: e = 4*eq .. 4*eq+3
        int mi = t >> 6;      // mention within tile (wave-uniform)
        const float4* W4 = reinterpret_cast<const float4*>(W) + eq;  // W[h][4eq..]
        const float* pm = &pooled[mi][0];
        float4 acc = make_float4(0.f, 0.f, 0.f, 0.f);
        #pragma unroll 8
        for (int h = 0; h < H; ++h) {
            float4 wv = W4[(size_t)h * (E / 4)];
            float p = pm[h];
            acc.x += p * wv.x; acc.y += p * wv.y;
            acc.z += p * wv.z; acc.w += p * wv.w;
        }
        float4 bv = reinterpret_cast<const float4*>(bias)[eq];
        float v0 = tanhf(acc.x + bv.x);
        float v1 = tanhf(acc.y + bv.y);
        float v2 = tanhf(acc.z + bv.z);
        float v3 = tanhf(acc.w + bv.w);

        int e0 = scoff + 4 * eq;
        float p[R];
        #pragma unroll
        for (int r = 0; r < R; ++r) {
            p[r] = v0 * Wsc[(size_t)(e0 + 0) * R + r] + v1 * Wsc[(size_t)(e0 + 1) * R + r]
                 + v2 * Wsc[(size_t)(e0 + 2) * R + r] + v3 * Wsc[(size_t)(e0 + 3) * R + r];
        }
        #pragma unroll
        for (int r = 0; r < R; ++r) {
            for (int off = 32; off; off >>= 1) p[r] += __shfl_down(p[r], off, 64);
        }
        if (eq == 0) {
            size_t row = ((size_t)z * B + b) * M + mg * MTA + mi;
            #pragma unroll
            for (int r = 0; r < R; ++r) sAB[row * R + r] = p[r];
        }
    } else {
        // ---- distance table: 4 distances per block, one wave each ----
        int d = (blk - A_SENT - A_GEMM) * 4 + (t >> 6);
        int k = t & 63;
        float v = emb[(size_t)d * D + k];
        #pragma unroll
        for (int r = 0; r < R; ++r) {
            float p = v * Wsc[(size_t)(2 * E + k) * R + r];
            for (int off = 32; off; off >>= 1) p += __shfl_down(p, off, 64);
            if (k == 0) sD[d * R + r] = p;
        }
    }
}

// ===========================================================================
// Kernel B: per (b, 8-mention tile): sent finish + sS dot in-block, pair max,
// atomicMax into out.  grid (12 * 8 = 96), block 256.
// ===========================================================================
__global__ void kB(const float* __restrict__ part, const float* __restrict__ Wsc,
                   const float* __restrict__ bsc,
                   const int* __restrict__ distance,
                   const float* __restrict__ sAB, const float* __restrict__ validAB,
                   const float* __restrict__ sD, float* __restrict__ out) {
    const int g = blockIdx.x % (M / MT4);
    const int b = blockIdx.x / (M / MT4);
    const int t = threadIdx.x;

    __shared__ float sent[H];          // 2 KB
    __shared__ float red[R][4];
    __shared__ float sSb[R];
    __shared__ float lB[M * R];        // 1.9 KB
    __shared__ float lD[MAXD * R];     // 12 KB
    __shared__ float lA[MT4 * R];
    __shared__ float lvA[MT4], lvB[M];

    // ---- sent max over z-partials (b-slice of part, L2-shared by 12 blocks) ----
    for (int h = t; h < H; h += 256) {
        float mx = -INFINITY;
        #pragma unroll 8
        for (int z = 0; z < NZ; ++z) mx = fmaxf(mx, part[((size_t)z * B + b) * H + h]);
        sent[h] = mx;
    }
    __syncthreads();

    // ---- sS[r] = sent . Wsc[576:1088] + bsc ----
    float acc[R] = {};
    for (int h = t; h < H; h += 256) {
        float v = sent[h];
        const float* w = Wsc + (size_t)(2 * E + D + h) * R;
        #pragma unroll
        for (int r = 0; r < R; ++r) acc[r] += v * w[r];
    }
    int wave = t >> 6, lane = t & 63;
    #pragma unroll
    for (int r = 0; r < R; ++r) {
        float v = acc[r];
        for (int off = 32; off; off >>= 1) v += __shfl_down(v, off, 64);
        if (lane == 0) red[r][wave] = v;
    }
    __syncthreads();
    if (t < R) sSb[t] = red[t][0] + red[t][1] + red[t][2] + red[t][3] + bsc[t];
    __syncthreads();

    // ---- stage tile operands ----
    for (int i = t; i < M * R; i += 256) lB[i] = sAB[((size_t)(B + b)) * M * R + i];
    for (int i = t; i < MAXD * R; i += 256) lD[i] = sD[i];
    if (t < MT4 * R) lA[t] = sAB[((size_t)b * M + g * MT4) * R + t] + sSb[t % R];
    if (t < MT4) lvA[t] = validAB[(size_t)b * M + g * MT4 + t];
    for (int i = t; i < M; i += 256) lvB[i] = validAB[((size_t)B + b) * M + i];
    __syncthreads();

    // ---- pair max over 8 x 96 ----
    float mx[R];
    #pragma unroll
    for (int r = 0; r < R; ++r) mx[r] = NEG_INF;

    #pragma unroll
    for (int it = 0; it < (MT4 * M) / 256; ++it) {
        int idx = it * 256 + t;           // [0, 768)
        int mi = idx / M, n = idx % M;
        int dist = distance[((size_t)b * M + g * MT4 + mi) * M + n];
        if (lvA[mi] > 0.f && lvB[n] > 0.f && dist >= 0 /*DIST_THRESH*/) {
            #pragma unroll
            for (int r = 0; r < R; ++r)
                mx[r] = fmaxf(mx[r], lA[mi * R + r] + lB[n * R + r] + lD[dist * R + r]);
        }
    }
    #pragma unroll
    for (int r = 0; r < R; ++r) {
        float v = mx[r];
        for (int off = 32; off; off >>= 1) v = fmaxf(v, __shfl_down(v, off, 64));
        if (lane == 0) red[r][wave] = v;
    }
    __syncthreads();
    if (t < R) {
        float v = fmaxf(fmaxf(red[t][0], red[t][1]), fmaxf(red[t][2], red[t][3]));
        atomicMaxFloat(out + b * R + t, v);
    }
}

// ---------------------------------------------------------------------------
extern "C" void kernel_launch(void* const* d_in, const int* in_sizes, int n_in,
                              void* d_out, int out_size, void* d_ws, size_t ws_size,
                              hipStream_t stream) {
    const float* node     = (const float*)d_in[0];
    const int*   cmap     = (const int*)  d_in[1];
    const float* cmask    = (const float*)d_in[2];
    const int*   dmap     = (const int*)  d_in[3];
    const float* dmask    = (const float*)d_in[4];
    const int*   distance = (const int*)  d_in[5];
    const float* Wc       = (const float*)d_in[6];
    const float* bc       = (const float*)d_in[7];
    const float* Wd       = (const float*)d_in[8];
    const float* bd       = (const float*)d_in[9];
    const float* Wsc      = (const float*)d_in[10];
    const float* bsc      = (const float*)d_in[11];
    const float* emb      = (const float*)d_in[12];
    float* out = (float*)d_out;

    // workspace layout (floats): total ~1.1 MB
    float* ws      = (float*)d_ws;
    float* part    = ws;                             // NZ*B*H   = 262144
    float* sAB     = part + (size_t)NZ * B * H;      // 2*B*M*R  = 7680
    float* validAB = sAB + 2 * B * M * R;            // 2*B*M    = 1536
    float* sD      = validAB + 2 * B * M;            // MAXD*R   = 3000

    hipLaunchKernelGGL(kA, dim3(A_GRID), dim3(256), 0, stream,
                       node, cmap, cmask, dmap, dmask, Wc, bc, Wd, bd, Wsc, emb,
                       part, sAB, validAB, sD, out);
    hipLaunchKernelGGL(kB, dim3((M / MT4) * B), dim3(256), 0, stream,
                       part, Wsc, bsc, distance, sAB, validAB, sD, out);
}

// Round 8
// 60.196 us; speedup vs baseline: 3.0462x; 1.3257x over previous
//
#include <hip/hip_runtime.h>
#include <math.h>

// Problem constants (from reference setup_inputs)
constexpr int B = 8, N = 2048, H = 512, M = 96, S = 16;
constexpr int E = 256, D = 64, R = 5, MAXD = 600;
constexpr int NZ = 64;            // n-splits for sent max partial
constexpr int NCHUNK = N / NZ;    // 32
constexpr int MTA = 4;            // mentions per fused gemm block
constexpr int MT4 = 8;            // m-rows per final-max tile
constexpr float NEG_INF = -1e10f;

constexpr int A_GEMM = 2 * B * (M / MTA);   // 384 fused entity blocks (FIRST)
constexpr int A_SENT = 256;                 // sent-partial blocks (2 z each)
constexpr int A_DIST = MAXD / 4;            // 150
constexpr int A_GRID = A_GEMM + A_SENT + A_DIST;   // 790

__device__ inline void atomicMaxFloat(float* addr, float val) {
    int* ai = (int*)addr;
    int old = *ai;
    while (__int_as_float(old) < val) {
        int assumed = old;
        old = atomicCAS(ai, assumed, __float_as_int(val));
        if (old == assumed) break;
    }
}

// ===========================================================================
// Kernel A: fused pool+GEMM+tanh+proj | sent-partial max | dist table | out init
// ===========================================================================
__global__ void kA(const float* __restrict__ node,
                   const int* __restrict__ cmap, const float* __restrict__ cmask,
                   const int* __restrict__ dmap, const float* __restrict__ dmask,
                   const float* __restrict__ Wc, const float* __restrict__ bc,
                   const float* __restrict__ Wd, const float* __restrict__ bd,
                   const float* __restrict__ Wsc, const float* __restrict__ emb,
                   float* __restrict__ part, float* __restrict__ sAB,
                   float* __restrict__ validAB, float* __restrict__ sD,
                   float* __restrict__ out) {
    const int blk = blockIdx.x;
    const int t = threadIdx.x;

    if (blk == 0 && t < B * R) out[t] = NEG_INF;   // init for kB's atomicMax

    if (blk < A_GEMM) {
        // ---- fused: gather/pool 4 mentions -> GEMM (h-split waves) -> tanh -> proj
        int j  = blk;
        int mg = j % (M / MTA);
        int b  = (j / (M / MTA)) % B;
        int z  = j / ((M / MTA) * B);
        const float* W    = z ? Wd : Wc;
        const float* bias = z ? bd : bc;
        const int*   map  = z ? dmap  : cmap;
        const float* mask = z ? dmask : cmask;
        int scoff = z ? E : 0;

        __shared__ float pooled[MTA][H];       // 8 KB
        __shared__ float red4[4][MTA][E];      // 16 KB (per-wave partial dots)
        __shared__ int   smap[MTA][S];
        __shared__ float smask[MTA][S];

        if (t < MTA * S) {
            int mi = t >> 4, s = t & 15;
            size_t off = ((size_t)b * M + mg * MTA + mi) * S + s;
            smap[mi][s]  = map[off];
            smask[mi][s] = mask[off];
        }
        __syncthreads();

        // pool: thread t = float2 index over H (256 * 2 = 512)
        #pragma unroll
        for (int mi = 0; mi < MTA; ++mi) {
            float a0 = 0.f, a1 = 0.f;
            #pragma unroll
            for (int s = 0; s < S; ++s) {
                float mk = smask[mi][s];
                const float2 v = reinterpret_cast<const float2*>(
                    node + ((size_t)b * N + smap[mi][s]) * H)[t];
                a0 += mk * v.x; a1 += mk * v.y;
            }
            reinterpret_cast<float2*>(&pooled[mi][0])[t] = make_float2(a0, a1);
        }
        if (t < MTA) {
            float ms = 0.f;
            #pragma unroll
            for (int s = 0; s < S; ++s) ms += smask[t][s];
            validAB[((size_t)z * B + b) * M + mg * MTA + t] = (ms > 0.f) ? 1.f : 0.f;
        }
        __syncthreads();

        // GEMM: wave = h-chunk (128 rows), lane = e-quad, all 4 mentions in regs.
        const int eq = t & 63;       // e-quad: e = 4*eq .. 4*eq+3
        const int w  = t >> 6;       // h-chunk index
        const int h0 = w * (H / 4);
        const float4* W4 = reinterpret_cast<const float4*>(W) + eq;
        float4 acc[MTA];
        #pragma unroll
        for (int mi = 0; mi < MTA; ++mi) acc[mi] = make_float4(0.f, 0.f, 0.f, 0.f);

        #pragma unroll 8
        for (int hh = 0; hh < H / 4; ++hh) {
            int h = h0 + hh;
            float4 wv = W4[(size_t)h * (E / 4)];
            #pragma unroll
            for (int mi = 0; mi < MTA; ++mi) {
                float p = pooled[mi][h];                 // wave-uniform broadcast
                acc[mi].x += p * wv.x; acc[mi].y += p * wv.y;
                acc[mi].z += p * wv.z; acc[mi].w += p * wv.w;
            }
        }
        #pragma unroll
        for (int mi = 0; mi < MTA; ++mi)
            reinterpret_cast<float4*>(&red4[w][mi][0])[eq] = acc[mi];
        __syncthreads();

        // wave w finishes mention mi = w: sum 4 partials, tanh, rank-5 proj
        {
            const int mi = w;
            float4 dv = reinterpret_cast<const float4*>(&red4[0][mi][0])[eq];
            #pragma unroll
            for (int ww = 1; ww < 4; ++ww) {
                float4 v = reinterpret_cast<const float4*>(&red4[ww][mi][0])[eq];
                dv.x += v.x; dv.y += v.y; dv.z += v.z; dv.w += v.w;
            }
            float4 bv = reinterpret_cast<const float4*>(bias)[eq];
            float v0 = tanhf(dv.x + bv.x);
            float v1 = tanhf(dv.y + bv.y);
            float v2 = tanhf(dv.z + bv.z);
            float v3 = tanhf(dv.w + bv.w);

            int e0 = scoff + 4 * eq;
            float p[R];
            #pragma unroll
            for (int r = 0; r < R; ++r) {
                p[r] = v0 * Wsc[(size_t)(e0 + 0) * R + r] + v1 * Wsc[(size_t)(e0 + 1) * R + r]
                     + v2 * Wsc[(size_t)(e0 + 2) * R + r] + v3 * Wsc[(size_t)(e0 + 3) * R + r];
            }
            #pragma unroll
            for (int r = 0; r < R; ++r) {
                for (int off = 32; off; off >>= 1) p[r] += __shfl_down(p[r], off, 64);
            }
            if (eq == 0) {
                size_t row = ((size_t)z * B + b) * M + mg * MTA + mi;
                #pragma unroll
                for (int r = 0; r < R; ++r) sAB[row * R + r] = p[r];
            }
        }
    } else if (blk < A_GEMM + A_SENT) {
        // ---- sent partial max: block covers (b, 2 z-chunks) ----
        int sb = blk - A_GEMM;
        int b = sb >> 5;
        int z = ((sb & 31) << 1) + (t >> 7);
        int tt = t & 127;   // float4 index over H
        const float4* p = reinterpret_cast<const float4*>(
            node + ((size_t)b * N + (size_t)z * NCHUNK) * H) + tt;
        float4 mx = p[0];
        #pragma unroll
        for (int n = 1; n < NCHUNK; ++n) {
            float4 v = p[(size_t)n * (H / 4)];
            mx.x = fmaxf(mx.x, v.x); mx.y = fmaxf(mx.y, v.y);
            mx.z = fmaxf(mx.z, v.z); mx.w = fmaxf(mx.w, v.w);
        }
        reinterpret_cast<float4*>(part + ((size_t)z * B + b) * H)[tt] = mx;
    } else {
        // ---- distance table: 4 distances per block, one wave each ----
        int d = (blk - A_GEMM - A_SENT) * 4 + (t >> 6);
        int k = t & 63;
        float v = emb[(size_t)d * D + k];
        #pragma unroll
        for (int r = 0; r < R; ++r) {
            float p = v * Wsc[(size_t)(2 * E + k) * R + r];
            for (int off = 32; off; off >>= 1) p += __shfl_down(p, off, 64);
            if (k == 0) sD[d * R + r] = p;
        }
    }
}

// ===========================================================================
// Kernel B: per (b, 8-mention tile): sent finish + sS dot in-block, pair max,
// atomicMax into out.  grid (12 * 8 = 96), block 256.
// ===========================================================================
__global__ void kB(const float* __restrict__ part, const float* __restrict__ Wsc,
                   const float* __restrict__ bsc,
                   const int* __restrict__ distance,
                   const float* __restrict__ sAB, const float* __restrict__ validAB,
                   const float* __restrict__ sD, float* __restrict__ out) {
    const int g = blockIdx.x % (M / MT4);
    const int b = blockIdx.x / (M / MT4);
    const int t = threadIdx.x;

    __shared__ float sent[H];          // 2 KB
    __shared__ float red[R][4];
    __shared__ float sSb[R];
    __shared__ float lB[M * R];        // 1.9 KB
    __shared__ float lD[MAXD * R];     // 12 KB
    __shared__ float lA[MT4 * R];
    __shared__ float lvA[MT4], lvB[M];

    // ---- sent max over z-partials (b-slice of part, L2-shared by 12 blocks) ----
    for (int h = t; h < H; h += 256) {
        float mx = -INFINITY;
        #pragma unroll 8
        for (int z = 0; z < NZ; ++z) mx = fmaxf(mx, part[((size_t)z * B + b) * H + h]);
        sent[h] = mx;
    }
    __syncthreads();

    // ---- sS[r] = sent . Wsc[576:1088] + bsc ----
    float acc[R] = {};
    for (int h = t; h < H; h += 256) {
        float v = sent[h];
        const float* w = Wsc + (size_t)(2 * E + D + h) * R;
        #pragma unroll
        for (int r = 0; r < R; ++r) acc[r] += v * w[r];
    }
    int wave = t >> 6, lane = t & 63;
    #pragma unroll
    for (int r = 0; r < R; ++r) {
        float v = acc[r];
        for (int off = 32; off; off >>= 1) v += __shfl_down(v, off, 64);
        if (lane == 0) red[r][wave] = v;
    }
    __syncthreads();
    if (t < R) sSb[t] = red[t][0] + red[t][1] + red[t][2] + red[t][3] + bsc[t];
    __syncthreads();

    // ---- stage tile operands ----
    for (int i = t; i < M * R; i += 256) lB[i] = sAB[((size_t)(B + b)) * M * R + i];
    for (int i = t; i < MAXD * R; i += 256) lD[i] = sD[i];
    if (t < MT4 * R) lA[t] = sAB[((size_t)b * M + g * MT4) * R + t] + sSb[t % R];
    if (t < MT4) lvA[t] = validAB[(size_t)b * M + g * MT4 + t];
    for (int i = t; i < M; i += 256) lvB[i] = validAB[((size_t)B + b) * M + i];
    __syncthreads();

    // ---- pair max over 8 x 96 ----
    float mx[R];
    #pragma unroll
    for (int r = 0; r < R; ++r) mx[r] = NEG_INF;

    #pragma unroll
    for (int it = 0; it < (MT4 * M) / 256; ++it) {
        int idx = it * 256 + t;           // [0, 768)
        int mi = idx / M, n = idx % M;
        int dist = distance[((size_t)b * M + g * MT4 + mi) * M + n];
        if (lvA[mi] > 0.f && lvB[n] > 0.f && dist >= 0 /*DIST_THRESH*/) {
            #pragma unroll
            for (int r = 0; r < R; ++r)
                mx[r] = fmaxf(mx[r], lA[mi * R + r] + lB[n * R + r] + lD[dist * R + r]);
        }
    }
    #pragma unroll
    for (int r = 0; r < R; ++r) {
        float v = mx[r];
        for (int off = 32; off; off >>= 1) v = fmaxf(v, __shfl_down(v, off, 64));
        if (lane == 0) red[r][wave] = v;
    }
    __syncthreads();
    if (t < R) {
        float v = fmaxf(fmaxf(red[t][0], red[t][1]), fmaxf(red[t][2], red[t][3]));
        atomicMaxFloat(out + b * R + t, v);
    }
}

// ---------------------------------------------------------------------------
extern "C" void kernel_launch(void* const* d_in, const int* in_sizes, int n_in,
                              void* d_out, int out_size, void* d_ws, size_t ws_size,
                              hipStream_t stream) {
    const float* node     = (const float*)d_in[0];
    const int*   cmap     = (const int*)  d_in[1];
    const float* cmask    = (const float*)d_in[2];
    const int*   dmap     = (const int*)  d_in[3];
    const float* dmask    = (const float*)d_in[4];
    const int*   distance = (const int*)  d_in[5];
    const float* Wc       = (const float*)d_in[6];
    const float* bc       = (const float*)d_in[7];
    const float* Wd       = (const float*)d_in[8];
    const float* bd       = (const float*)d_in[9];
    const float* Wsc      = (const float*)d_in[10];
    const float* bsc      = (const float*)d_in[11];
    const float* emb      = (const float*)d_in[12];
    float* out = (float*)d_out;

    // workspace layout (floats): total ~1.1 MB
    float* ws      = (float*)d_ws;
    float* part    = ws;                             // NZ*B*H   = 262144
    float* sAB     = part + (size_t)NZ * B * H;      // 2*B*M*R  = 7680
    float* validAB = sAB + 2 * B * M * R;            // 2*B*M    = 1536
    float* sD      = validAB + 2 * B * M;            // MAXD*R   = 3000

    hipLaunchKernelGGL(kA, dim3(A_GRID), dim3(256), 0, stream,
                       node, cmap, cmask, dmap, dmask, Wc, bc, Wd, bd, Wsc, emb,
                       part, sAB, validAB, sD, out);
    hipLaunchKernelGGL(kB, dim3((M / MT4) * B), dim3(256), 0, stream,
                       part, Wsc, bsc, distance, sAB, validAB, sD, out);
}

// Round 9
// 59.086 us; speedup vs baseline: 3.1035x; 1.0188x over previous
//
#include <hip/hip_runtime.h>
#include <math.h>

// Problem constants (from reference setup_inputs)
constexpr int B = 8, N = 2048, H = 512, M = 96, S = 16;
constexpr int E = 256, D = 64, R = 5, MAXD = 600;
constexpr int NZ = 64;            // n-splits for sent max partial
constexpr int NCHUNK = N / NZ;    // 32
constexpr int MTA = 3;            // mentions per fused gemm block (96/3=32 groups)
constexpr int MT4 = 8;            // m-rows per final-max tile
constexpr float NEG_INF = -1e10f;

constexpr int A_GEMM = 2 * B * (M / MTA);   // 512 fused entity blocks = exactly 2/CU
constexpr int A_SENT = 256;                 // sent-partial blocks (2 z each)
constexpr int A_DIST = MAXD / 4;            // 150
constexpr int A_GRID = A_GEMM + A_SENT + A_DIST;   // 918

__device__ inline void atomicMaxFloat(float* addr, float val) {
    int* ai = (int*)addr;
    int old = *ai;
    while (__int_as_float(old) < val) {
        int assumed = old;
        old = atomicCAS(ai, assumed, __float_as_int(val));
        if (old == assumed) break;
    }
}

// ===========================================================================
// Kernel A: fused pool+GEMM+tanh+proj | sent-partial max | dist table | out init
// ===========================================================================
__global__ __launch_bounds__(256)
void kA(const float* __restrict__ node,
        const int* __restrict__ cmap, const float* __restrict__ cmask,
        const int* __restrict__ dmap, const float* __restrict__ dmask,
        const float* __restrict__ Wc, const float* __restrict__ bc,
        const float* __restrict__ Wd, const float* __restrict__ bd,
        const float* __restrict__ Wsc, const float* __restrict__ emb,
        float* __restrict__ part, float* __restrict__ sAB,
        float* __restrict__ validAB, float* __restrict__ sD,
        float* __restrict__ out) {
    const int blk = blockIdx.x;
    const int t = threadIdx.x;

    if (blk == 0 && t < B * R) out[t] = NEG_INF;   // init for kB's atomicMax

    if (blk < A_GEMM) {
        // ---- fused: gather/pool 3 mentions -> GEMM (h-split waves) -> tanh -> proj
        int j  = blk;
        int mg = j % (M / MTA);
        int b  = (j / (M / MTA)) % B;
        int z  = j / ((M / MTA) * B);
        const float* W    = z ? Wd : Wc;
        const float* bias = z ? bd : bc;
        const int*   map  = z ? dmap  : cmap;
        const float* mask = z ? dmask : cmask;
        int scoff = z ? E : 0;

        __shared__ float pooled[MTA][H];       // 6 KB
        __shared__ float red4[4][MTA][E];      // 12 KB (per-wave partial dots)
        __shared__ int   smap[MTA][S];
        __shared__ float smask[MTA][S];

        if (t < MTA * S) {
            int mi = t >> 4, s = t & 15;
            size_t off = ((size_t)b * M + mg * MTA + mi) * S + s;
            smap[mi][s]  = map[off];
            smask[mi][s] = mask[off];
        }
        __syncthreads();

        // pool: thread t = float2 index over H (256 * 2 = 512)
        #pragma unroll
        for (int mi = 0; mi < MTA; ++mi) {
            float a0 = 0.f, a1 = 0.f;
            #pragma unroll
            for (int s = 0; s < S; ++s) {
                float mk = smask[mi][s];
                const float2 v = reinterpret_cast<const float2*>(
                    node + ((size_t)b * N + smap[mi][s]) * H)[t];
                a0 += mk * v.x; a1 += mk * v.y;
            }
            reinterpret_cast<float2*>(&pooled[mi][0])[t] = make_float2(a0, a1);
        }
        if (t < MTA) {
            float ms = 0.f;
            #pragma unroll
            for (int s = 0; s < S; ++s) ms += smask[t][s];
            validAB[((size_t)z * B + b) * M + mg * MTA + t] = (ms > 0.f) ? 1.f : 0.f;
        }
        __syncthreads();

        // GEMM: wave = h-chunk (128 rows), lane = e-quad, 3 mentions in regs.
        const int eq = t & 63;       // e-quad: e = 4*eq .. 4*eq+3
        const int w  = t >> 6;       // h-chunk index
        const int h0 = w * (H / 4);
        const float4* W4 = reinterpret_cast<const float4*>(W) + eq;
        float4 acc0 = make_float4(0.f, 0.f, 0.f, 0.f);
        float4 acc1 = acc0, acc2 = acc0;

        #pragma unroll 4
        for (int hh4 = 0; hh4 < (H / 4) / 4; ++hh4) {   // 32 iters of 4 h's
            int h = h0 + hh4 * 4;
            const float4 p0 = *reinterpret_cast<const float4*>(&pooled[0][h]);
            const float4 p1 = *reinterpret_cast<const float4*>(&pooled[1][h]);
            const float4 p2 = *reinterpret_cast<const float4*>(&pooled[2][h]);
            const float4 w0 = W4[(size_t)(h + 0) * (E / 4)];
            const float4 w1 = W4[(size_t)(h + 1) * (E / 4)];
            const float4 w2 = W4[(size_t)(h + 2) * (E / 4)];
            const float4 w3 = W4[(size_t)(h + 3) * (E / 4)];
            acc0.x += p0.x*w0.x + p0.y*w1.x + p0.z*w2.x + p0.w*w3.x;
            acc0.y += p0.x*w0.y + p0.y*w1.y + p0.z*w2.y + p0.w*w3.y;
            acc0.z += p0.x*w0.z + p0.y*w1.z + p0.z*w2.z + p0.w*w3.z;
            acc0.w += p0.x*w0.w + p0.y*w1.w + p0.z*w2.w + p0.w*w3.w;
            acc1.x += p1.x*w0.x + p1.y*w1.x + p1.z*w2.x + p1.w*w3.x;
            acc1.y += p1.x*w0.y + p1.y*w1.y + p1.z*w2.y + p1.w*w3.y;
            acc1.z += p1.x*w0.z + p1.y*w1.z + p1.z*w2.z + p1.w*w3.z;
            acc1.w += p1.x*w0.w + p1.y*w1.w + p1.z*w2.w + p1.w*w3.w;
            acc2.x += p2.x*w0.x + p2.y*w1.x + p2.z*w2.x + p2.w*w3.x;
            acc2.y += p2.x*w0.y + p2.y*w1.y + p2.z*w2.y + p2.w*w3.y;
            acc2.z += p2.x*w0.z + p2.y*w1.z + p2.z*w2.z + p2.w*w3.z;
            acc2.w += p2.x*w0.w + p2.y*w1.w + p2.z*w2.w + p2.w*w3.w;
        }
        reinterpret_cast<float4*>(&red4[w][0][0])[eq] = acc0;
        reinterpret_cast<float4*>(&red4[w][1][0])[eq] = acc1;
        reinterpret_cast<float4*>(&red4[w][2][0])[eq] = acc2;
        __syncthreads();

        // wave w < MTA finishes mention mi = w: sum 4 partials, tanh, rank-5 proj
        if (w < MTA) {
            const int mi = w;
            float4 dv = reinterpret_cast<const float4*>(&red4[0][mi][0])[eq];
            #pragma unroll
            for (int ww = 1; ww < 4; ++ww) {
                float4 v = reinterpret_cast<const float4*>(&red4[ww][mi][0])[eq];
                dv.x += v.x; dv.y += v.y; dv.z += v.z; dv.w += v.w;
            }
            float4 bv = reinterpret_cast<const float4*>(bias)[eq];
            float v0 = tanhf(dv.x + bv.x);
            float v1 = tanhf(dv.y + bv.y);
            float v2 = tanhf(dv.z + bv.z);
            float v3 = tanhf(dv.w + bv.w);

            int e0 = scoff + 4 * eq;
            float p[R];
            #pragma unroll
            for (int r = 0; r < R; ++r) {
                p[r] = v0 * Wsc[(size_t)(e0 + 0) * R + r] + v1 * Wsc[(size_t)(e0 + 1) * R + r]
                     + v2 * Wsc[(size_t)(e0 + 2) * R + r] + v3 * Wsc[(size_t)(e0 + 3) * R + r];
            }
            #pragma unroll
            for (int r = 0; r < R; ++r) {
                for (int off = 32; off; off >>= 1) p[r] += __shfl_down(p[r], off, 64);
            }
            if (eq == 0) {
                size_t row = ((size_t)z * B + b) * M + mg * MTA + mi;
                #pragma unroll
                for (int r = 0; r < R; ++r) sAB[row * R + r] = p[r];
            }
        }
    } else if (blk < A_GEMM + A_SENT) {
        // ---- sent partial max: block covers (b, 2 z-chunks) ----
        int sb = blk - A_GEMM;
        int b = sb >> 5;
        int z = ((sb & 31) << 1) + (t >> 7);
        int tt = t & 127;   // float4 index over H
        const float4* p = reinterpret_cast<const float4*>(
            node + ((size_t)b * N + (size_t)z * NCHUNK) * H) + tt;
        float4 mx = p[0];
        #pragma unroll
        for (int n = 1; n < NCHUNK; ++n) {
            float4 v = p[(size_t)n * (H / 4)];
            mx.x = fmaxf(mx.x, v.x); mx.y = fmaxf(mx.y, v.y);
            mx.z = fmaxf(mx.z, v.z); mx.w = fmaxf(mx.w, v.w);
        }
        reinterpret_cast<float4*>(part + ((size_t)z * B + b) * H)[tt] = mx;
    } else {
        // ---- distance table: 4 distances per block, one wave each ----
        int d = (blk - A_GEMM - A_SENT) * 4 + (t >> 6);
        int k = t & 63;
        float v = emb[(size_t)d * D + k];
        #pragma unroll
        for (int r = 0; r < R; ++r) {
            float p = v * Wsc[(size_t)(2 * E + k) * R + r];
            for (int off = 32; off; off >>= 1) p += __shfl_down(p, off, 64);
            if (k == 0) sD[d * R + r] = p;
        }
    }
}

// ===========================================================================
// Kernel B: per (b, 8-mention tile): sent finish + sS dot in-block, pair max,
// atomicMax into out.  grid (12 * 8 = 96), block 256.
// ===========================================================================
__global__ void kB(const float* __restrict__ part, const float* __restrict__ Wsc,
                   const float* __restrict__ bsc,
                   const int* __restrict__ distance,
                   const float* __restrict__ sAB, const float* __restrict__ validAB,
                   const float* __restrict__ sD, float* __restrict__ out) {
    const int g = blockIdx.x % (M / MT4);
    const int b = blockIdx.x / (M / MT4);
    const int t = threadIdx.x;

    __shared__ float sent[H];          // 2 KB
    __shared__ float red[R][4];
    __shared__ float sSb[R];
    __shared__ float lB[M * R];        // 1.9 KB
    __shared__ float lD[MAXD * R];     // 12 KB
    __shared__ float lA[MT4 * R];
    __shared__ float lvA[MT4], lvB[M];

    // ---- sent max over z-partials (b-slice of part, L2-shared by 12 blocks) ----
    for (int h = t; h < H; h += 256) {
        float mx = -INFINITY;
        #pragma unroll 8
        for (int z = 0; z < NZ; ++z) mx = fmaxf(mx, part[((size_t)z * B + b) * H + h]);
        sent[h] = mx;
    }
    __syncthreads();

    // ---- sS[r] = sent . Wsc[576:1088] + bsc ----
    float acc[R] = {};
    for (int h = t; h < H; h += 256) {
        float v = sent[h];
        const float* w = Wsc + (size_t)(2 * E + D + h) * R;
        #pragma unroll
        for (int r = 0; r < R; ++r) acc[r] += v * w[r];
    }
    int wave = t >> 6, lane = t & 63;
    #pragma unroll
    for (int r = 0; r < R; ++r) {
        float v = acc[r];
        for (int off = 32; off; off >>= 1) v += __shfl_down(v, off, 64);
        if (lane == 0) red[r][wave] = v;
    }
    __syncthreads();
    if (t < R) sSb[t] = red[t][0] + red[t][1] + red[t][2] + red[t][3] + bsc[t];
    __syncthreads();

    // ---- stage tile operands ----
    for (int i = t; i < M * R; i += 256) lB[i] = sAB[((size_t)(B + b)) * M * R + i];
    for (int i = t; i < MAXD * R; i += 256) lD[i] = sD[i];
    if (t < MT4 * R) lA[t] = sAB[((size_t)b * M + g * MT4) * R + t] + sSb[t % R];
    if (t < MT4) lvA[t] = validAB[(size_t)b * M + g * MT4 + t];
    for (int i = t; i < M; i += 256) lvB[i] = validAB[((size_t)B + b) * M + i];
    __syncthreads();

    // ---- pair max over 8 x 96 ----
    float mx[R];
    #pragma unroll
    for (int r = 0; r < R; ++r) mx[r] = NEG_INF;

    #pragma unroll
    for (int it = 0; it < (MT4 * M) / 256; ++it) {
        int idx = it * 256 + t;           // [0, 768)
        int mi = idx / M, n = idx % M;
        int dist = distance[((size_t)b * M + g * MT4 + mi) * M + n];
        if (lvA[mi] > 0.f && lvB[n] > 0.f && dist >= 0 /*DIST_THRESH*/) {
            #pragma unroll
            for (int r = 0; r < R; ++r)
                mx[r] = fmaxf(mx[r], lA[mi * R + r] + lB[n * R + r] + lD[dist * R + r]);
        }
    }
    #pragma unroll
    for (int r = 0; r < R; ++r) {
        float v = mx[r];
        for (int off = 32; off; off >>= 1) v = fmaxf(v, __shfl_down(v, off, 64));
        if (lane == 0) red[r][wave] = v;
    }
    __syncthreads();
    if (t < R) {
        float v = fmaxf(fmaxf(red[t][0], red[t][1]), fmaxf(red[t][2], red[t][3]));
        atomicMaxFloat(out + b * R + t, v);
    }
}

// ---------------------------------------------------------------------------
extern "C" void kernel_launch(void* const* d_in, const int* in_sizes, int n_in,
                              void* d_out, int out_size, void* d_ws, size_t ws_size,
                              hipStream_t stream) {
    const float* node     = (const float*)d_in[0];
    const int*   cmap     = (const int*)  d_in[1];
    const float* cmask    = (const float*)d_in[2];
    const int*   dmap     = (const int*)  d_in[3];
    const float* dmask    = (const float*)d_in[4];
    const int*   distance = (const int*)  d_in[5];
    const float* Wc       = (const float*)d_in[6];
    const float* bc       = (const float*)d_in[7];
    const float* Wd       = (const float*)d_in[8];
    const float* bd       = (const float*)d_in[9];
    const float* Wsc      = (const float*)d_in[10];
    const float* bsc      = (const float*)d_in[11];
    const float* emb      = (const float*)d_in[12];
    float* out = (float*)d_out;

    // workspace layout (floats): total ~1.1 MB
    float* ws      = (float*)d_ws;
    float* part    = ws;                             // NZ*B*H   = 262144
    float* sAB     = part + (size_t)NZ * B * H;      // 2*B*M*R  = 7680
    float* validAB = sAB + 2 * B * M * R;            // 2*B*M    = 1536
    float* sD      = validAB + 2 * B * M;            // MAXD*R   = 3000

    hipLaunchKernelGGL(kA, dim3(A_GRID), dim3(256), 0, stream,
                       node, cmap, cmask, dmap, dmask, Wc, bc, Wd, bd, Wsc, emb,
                       part, sAB, validAB, sD, out);
    hipLaunchKernelGGL(kB, dim3((M / MT4) * B), dim3(256), 0, stream,
                       part, Wsc, bsc, distance, sAB, validAB, sD, out);
}